// Round 1
// baseline (1076.036 us; speedup 1.0000x reference)
//
#include <hip/hip_runtime.h>

#define DFEAT 256

// ---------------- CSR construction ----------------

__global__ void k_count(const int* __restrict__ ei0, int E, int* __restrict__ cnt) {
  int i = blockIdx.x * blockDim.x + threadIdx.x;
  if (i < E) atomicAdd(&cnt[ei0[i]], 1);
}

__global__ __launch_bounds__(1024) void k_scan(const int* __restrict__ cnt, int N, int E,
                                               int* __restrict__ rowptr,
                                               float* __restrict__ dis) {
  __shared__ int sums[1024];
  int t = threadIdx.x;
  int chunk = (N + 1023) >> 10;
  int lo = t * chunk;
  int hi = min(N, lo + chunk);
  int s = 0;
  for (int i = lo; i < hi; ++i) s += cnt[i];
  sums[t] = s;
  __syncthreads();
  // Hillis-Steele inclusive scan over 1024 partials
  for (int o = 1; o < 1024; o <<= 1) {
    int u = (t >= o) ? sums[t - o] : 0;
    __syncthreads();
    sums[t] += u;
    __syncthreads();
  }
  int run = (t == 0) ? 0 : sums[t - 1];
  for (int i = lo; i < hi; ++i) {
    rowptr[i] = run;
    int c = cnt[i];
    run += c;
    dis[i] = rsqrtf((float)(c + 1));  // deg includes the appended self loop
  }
  if (t == 0) rowptr[N] = E;
}

__global__ void k_scatter(const int* __restrict__ ei0, const int* __restrict__ ei1, int E,
                          const int* __restrict__ rowptr, int* __restrict__ cursor,
                          const float* __restrict__ dis,
                          int* __restrict__ cols, float* __restrict__ vals) {
  int i = blockIdx.x * blockDim.x + threadIdx.x;
  if (i >= E) return;
  int r = ei0[i];
  int c = ei1[i];
  int pos = rowptr[r] + atomicAdd(&cursor[r], 1);
  cols[pos] = c;
  // L = I - D^-1/2 A D^-1/2 ; +1 applies to EVERY row==col entry (incl. dup self edges)
  vals[pos] = -dis[r] * dis[c] + (r == c ? 1.0f : 0.0f);
}

// ---------------- SpMM: y = alpha * (L v) + beta * w ----------------
// The appended self-loop edge contributes (1 - dis[r]^2) * v[r], handled here.

__global__ __launch_bounds__(DFEAT) void k_spmm(const float* __restrict__ v,
                                                const float* __restrict__ w,
                                                float* __restrict__ y,
                                                const int* __restrict__ rowptr,
                                                const int* __restrict__ cols,
                                                const float* __restrict__ vals,
                                                const float* __restrict__ dis,
                                                float alpha, float beta, int N) {
  int r = blockIdx.x;
  int d = threadIdx.x;
  size_t idx = (size_t)r * DFEAT + d;
  float dr = dis[r];
  float acc = (1.0f - dr * dr) * v[idx];
  int e0 = rowptr[r];
  int e1 = rowptr[r + 1];
  for (int e = e0; e < e1; ++e) {
    int c = cols[e];
    float lv = vals[e];
    acc += lv * v[(size_t)c * DFEAT + d];
  }
  float res = alpha * acc;
  if (beta != 0.0f) res += beta * w[idx];
  y[idx] = res;
}

// ---------------- GEMM: C (+)= A[N,256] @ W[256,256] (+ bias) ----------------
// 64x64 tile, 16x16 threads, 4x4 microtile, BK=32, f32 VALU.

__global__ __launch_bounds__(256) void k_gemm(const float* __restrict__ A,
                                              const float* __restrict__ W,
                                              const float* __restrict__ bias,
                                              float* __restrict__ C, int N,
                                              int accumulate, int addbias) {
  __shared__ float As[64][36];  // stride 36 floats: 16B-aligned rows, spread banks
  __shared__ float Bs[32][68];
  int tid = threadIdx.x;
  int tx = tid & 15;
  int ty = tid >> 4;
  int row0 = blockIdx.x * 64;
  int col0 = blockIdx.y * 64;

  float acc[4][4] = {};

  int sr = tid >> 2;         // A stage: row in tile 0..63
  int sk = (tid & 3) * 8;    // A stage: k offset 0,8,16,24
  int bk = tid >> 3;         // B stage: k 0..31
  int bc = (tid & 7) * 8;    // B stage: col offset

  for (int k0 = 0; k0 < DFEAT; k0 += 32) {
    int grow = row0 + sr;
    float4 a0 = make_float4(0.f, 0.f, 0.f, 0.f), a1 = a0;
    if (grow < N) {
      const float* src = A + (size_t)grow * DFEAT + k0 + sk;
      a0 = *(const float4*)src;
      a1 = *(const float4*)(src + 4);
    }
    const float* wsrc = W + (size_t)(k0 + bk) * DFEAT + col0 + bc;
    float4 b0 = *(const float4*)wsrc;
    float4 b1 = *(const float4*)(wsrc + 4);

    __syncthreads();  // previous iter's LDS reads done before overwrite
    *(float4*)&As[sr][sk] = a0;
    *(float4*)&As[sr][sk + 4] = a1;
    *(float4*)&Bs[bk][bc] = b0;
    *(float4*)&Bs[bk][bc + 4] = b1;
    __syncthreads();

#pragma unroll
    for (int k = 0; k < 32; ++k) {
      float ar[4];
#pragma unroll
      for (int i = 0; i < 4; ++i) ar[i] = As[ty * 4 + i][k];
      float4 bv = *(const float4*)&Bs[k][tx * 4];
      float br[4] = {bv.x, bv.y, bv.z, bv.w};
#pragma unroll
      for (int i = 0; i < 4; ++i)
#pragma unroll
        for (int j = 0; j < 4; ++j) acc[i][j] += ar[i] * br[j];
    }
  }

#pragma unroll
  for (int i = 0; i < 4; ++i) {
    int gr = row0 + ty * 4 + i;
    if (gr >= N) break;
    float* dst = C + (size_t)gr * DFEAT + col0 + tx * 4;
    float4 v = make_float4(acc[i][0], acc[i][1], acc[i][2], acc[i][3]);
    if (addbias) {
      const float* bp = bias + col0 + tx * 4;
      v.x += bp[0]; v.y += bp[1]; v.z += bp[2]; v.w += bp[3];
    }
    if (accumulate) {
      float4 c = *(const float4*)dst;
      v.x += c.x; v.y += c.y; v.z += c.z; v.w += c.w;
    }
    *(float4*)dst = v;
  }
}

// ---------------- launch ----------------

extern "C" void kernel_launch(void* const* d_in, const int* in_sizes, int n_in,
                              void* d_out, int out_size, void* d_ws, size_t ws_size,
                              hipStream_t stream) {
  const float* x = (const float*)d_in[0];
  const int* ei = (const int*)d_in[1];
  const float* weight = (const float*)d_in[2];
  const float* bias = (const float*)d_in[3];
  float* out = (float*)d_out;

  int N = in_sizes[0] / DFEAT;
  int E = in_sizes[1] / 2;
  const int* ei0 = ei;
  const int* ei1 = ei + E;

  char* ws = (char*)d_ws;
  size_t off = 0;
  auto alloc = [&](size_t bytes) {
    void* p = ws + off;
    off = (off + bytes + 255) & ~(size_t)255;
    return p;
  };
  int* cnt = (int*)alloc((size_t)2 * N * sizeof(int));  // cnt + cursor contiguous
  int* cursor = cnt + N;
  int* rowptr = (int*)alloc((size_t)(N + 1) * sizeof(int));
  float* dis = (float*)alloc((size_t)N * sizeof(float));
  int* cols = (int*)alloc((size_t)E * sizeof(int));
  float* vals = (float*)alloc((size_t)E * sizeof(float));
  float* B1 = (float*)alloc((size_t)N * DFEAT * sizeof(float));
  float* B2 = (float*)alloc((size_t)N * DFEAT * sizeof(float));

  hipMemsetAsync(cnt, 0, (size_t)2 * N * sizeof(int), stream);

  int eb = (E + 255) / 256;
  k_count<<<eb, 256, 0, stream>>>(ei0, E, cnt);
  k_scan<<<1, 1024, 0, stream>>>(cnt, N, E, rowptr, dis);
  k_scatter<<<eb, 256, 0, stream>>>(ei0, ei1, E, rowptr, cursor, dis, cols, vals);

  dim3 ggrid((N + 63) / 64, DFEAT / 64);
  // out = x @ W0 (+ bias, zeros anyway)
  k_gemm<<<ggrid, 256, 0, stream>>>(x, weight + 0 * DFEAT * DFEAT, bias, out, N, 0, 1);
  // B1 = T1 = L x
  k_spmm<<<N, DFEAT, 0, stream>>>(x, x, B1, rowptr, cols, vals, dis, 1.0f, 0.0f, N);
  k_gemm<<<ggrid, 256, 0, stream>>>(B1, weight + 1 * DFEAT * DFEAT, bias, out, N, 1, 0);
  // B2 = T2 = 2 L T1 - x
  k_spmm<<<N, DFEAT, 0, stream>>>(B1, x, B2, rowptr, cols, vals, dis, 2.0f, -1.0f, N);
  k_gemm<<<ggrid, 256, 0, stream>>>(B2, weight + 2 * DFEAT * DFEAT, bias, out, N, 1, 0);
  // B1 = T3 = 2 L T2 - T1 (in-place over T1: beta-term is same-position read)
  k_spmm<<<N, DFEAT, 0, stream>>>(B2, B1, B1, rowptr, cols, vals, dis, 2.0f, -1.0f, N);
  k_gemm<<<ggrid, 256, 0, stream>>>(B1, weight + 3 * DFEAT * DFEAT, bias, out, N, 1, 0);
}

// Round 2
// 553.077 us; speedup vs baseline: 1.9455x; 1.9455x over previous
//
#include <hip/hip_runtime.h>
#include <hip/hip_bf16.h>

#define DFEAT 256

typedef __attribute__((ext_vector_type(8))) short bf16x8;
typedef __attribute__((ext_vector_type(4))) float f32x4;

__device__ __forceinline__ float bf2f(unsigned short u) {
  return __builtin_bit_cast(float, ((unsigned)u) << 16);
}
__device__ __forceinline__ unsigned short f2bf(float f) {
  __hip_bfloat16 h = __float2bfloat16(f);  // RTNE
  return *reinterpret_cast<unsigned short*>(&h);
}
__device__ __forceinline__ void gload_lds16(const void* g, void* l) {
  __builtin_amdgcn_global_load_lds(
      (const __attribute__((address_space(1))) void*)g,
      (__attribute__((address_space(3))) void*)l, 16, 0, 0);
}

// ---------------- CSR construction ----------------

__global__ void k_count(const int* __restrict__ ei0, int E, int* __restrict__ cnt) {
  int i = blockIdx.x * blockDim.x + threadIdx.x;
  if (i < E) atomicAdd(&cnt[ei0[i]], 1);
}

__global__ __launch_bounds__(1024) void k_scan(const int* __restrict__ cnt, int N, int E,
                                               int* __restrict__ rowptr,
                                               float* __restrict__ dis) {
  __shared__ int sums[1024];
  int t = threadIdx.x;
  int chunk = (N + 1023) >> 10;
  int lo = t * chunk;
  int hi = min(N, lo + chunk);
  int s = 0;
  for (int i = lo; i < hi; ++i) s += cnt[i];
  sums[t] = s;
  __syncthreads();
  for (int o = 1; o < 1024; o <<= 1) {
    int u = (t >= o) ? sums[t - o] : 0;
    __syncthreads();
    sums[t] += u;
    __syncthreads();
  }
  int run = (t == 0) ? 0 : sums[t - 1];
  for (int i = lo; i < hi; ++i) {
    rowptr[i] = run;
    int c = cnt[i];
    run += c;
    dis[i] = rsqrtf((float)(c + 1));  // deg includes appended self loop
  }
  if (t == 0) rowptr[N] = E;
}

__global__ void k_scatter(const int* __restrict__ ei0, const int* __restrict__ ei1, int E,
                          const int* __restrict__ rowptr, int* __restrict__ cursor,
                          const float* __restrict__ dis,
                          int* __restrict__ cols, float* __restrict__ vals) {
  int i = blockIdx.x * blockDim.x + threadIdx.x;
  if (i >= E) return;
  int r = ei0[i];
  int c = ei1[i];
  int pos = rowptr[r] + atomicAdd(&cursor[r], 1);
  cols[pos] = c;
  vals[pos] = -dis[r] * dis[c] + (r == c ? 1.0f : 0.0f);
}

// ---------------- converts ----------------

__global__ void k_f2bf(const float* __restrict__ src, unsigned short* __restrict__ dst,
                       int n4) {  // n4 = total/4
  int i = blockIdx.x * blockDim.x + threadIdx.x;
  if (i >= n4) return;
  float4 f = *(const float4*)(src + (size_t)i * 4);
  ushort4 u;
  u.x = f2bf(f.x); u.y = f2bf(f.y); u.z = f2bf(f.z); u.w = f2bf(f.w);
  *(ushort4*)(dst + (size_t)i * 4) = u;
}

// W[4][256][256] (g,k,n) -> WT[4][256][256] (g,n,k) bf16
__global__ void k_wt(const float* __restrict__ W, unsigned short* __restrict__ WT) {
  int idx = blockIdx.x * 256 + threadIdx.x;
  int n = idx & 255;
  int k = (idx >> 8) & 255;
  int g = idx >> 16;
  WT[(g << 16) | (n << 8) | k] = f2bf(W[idx]);
}

// ---------------- SpMM (bf16): y = alpha * (L v) + beta * w ----------------
// 256 threads = 4 edge slots x 64 lanes; lane covers 4 feats (ushort4, 8B).

__global__ __launch_bounds__(256) void k_spmm_bf(
    const unsigned short* __restrict__ v, const unsigned short* __restrict__ w,
    unsigned short* __restrict__ y,
    const int* __restrict__ rowptr, const int* __restrict__ cols,
    const float* __restrict__ vals, const float* __restrict__ dis,
    float alpha, float beta) {
  __shared__ float red[3][64][4];
  int r = blockIdx.x;
  int lane = threadIdx.x & 63;
  int s = threadIdx.x >> 6;
  int fo = lane * 4;
  float acc[4] = {0.f, 0.f, 0.f, 0.f};
  int e0 = rowptr[r], e1 = rowptr[r + 1];
  for (int e = e0 + s; e < e1; e += 4) {
    int c = cols[e];
    float lv = vals[e];
    ushort4 u = *(const ushort4*)(v + (size_t)c * DFEAT + fo);
    acc[0] += lv * bf2f(u.x);
    acc[1] += lv * bf2f(u.y);
    acc[2] += lv * bf2f(u.z);
    acc[3] += lv * bf2f(u.w);
  }
  if (s) *(float4*)&red[s - 1][lane][0] = make_float4(acc[0], acc[1], acc[2], acc[3]);
  __syncthreads();
  if (s == 0) {
    float dr = dis[r];
    float sc = 1.0f - dr * dr;  // self-loop Laplacian value
    ushort4 uv = *(const ushort4*)(v + (size_t)r * DFEAT + fo);
    unsigned short us[4] = {uv.x, uv.y, uv.z, uv.w};
    float wv[4] = {0.f, 0.f, 0.f, 0.f};
    if (beta != 0.0f) {
      ushort4 uw = *(const ushort4*)(w + (size_t)r * DFEAT + fo);
      wv[0] = bf2f(uw.x); wv[1] = bf2f(uw.y); wv[2] = bf2f(uw.z); wv[3] = bf2f(uw.w);
    }
    ushort4 o;
    unsigned short* op = &o.x;
#pragma unroll
    for (int j = 0; j < 4; ++j) {
      float a = acc[j] + red[0][lane][j] + red[1][lane][j] + red[2][lane][j];
      a += sc * bf2f(us[j]);
      op[j] = f2bf(alpha * a + beta * wv[j]);
    }
    *(ushort4*)(y + (size_t)r * DFEAT + fo) = o;
  }
}

// ---------------- fused MFMA GEMM: out = sum_g Ag @ Wg + bias ----------------
// 128x128 tile, 4 waves (2x2), BK=64, XOR-swizzled LDS, global_load_lds staging.

__global__ __launch_bounds__(256) void k_gemm4(
    const unsigned short* __restrict__ A0, const unsigned short* __restrict__ A1,
    const unsigned short* __restrict__ A2, const unsigned short* __restrict__ A3,
    const unsigned short* __restrict__ WT,  // [4][256][256] (g,n,k)
    const float* __restrict__ bias, float* __restrict__ C, int N) {
  __shared__ __align__(16) unsigned short As[128 * 64];  // [row][64k] bf16, swizzled
  __shared__ __align__(16) unsigned short Bs[128 * 64];
  int tid = threadIdx.x;
  int lane = tid & 63;
  int w = tid >> 6;
  int wm = w >> 1, wn = w & 1;
  int brow = blockIdx.x * 128;
  int bcol = blockIdx.y * 128;

  f32x4 acc[4][4] = {};

  // staging: lane l covers (row = r0 + l>>3, 16B slot l&7); source kbyte pre-swizzled
  int srow = w * 32 + (lane >> 3);                 // + c*8, local row
  int skb = ((lane & 7) ^ (lane >> 3)) << 4;       // swizzled kbyte in 128B row

  for (int it = 0; it < 16; ++it) {
    int g = it >> 2;
    int k0 = (it & 3) * 64;  // k element offset
    const unsigned short* Asrc = g == 0 ? A0 : g == 1 ? A1 : g == 2 ? A2 : A3;
    const unsigned short* Bsrc = WT + (g << 16);
    __syncthreads();  // previous compute done before restage
#pragma unroll
    for (int c = 0; c < 4; ++c) {
      int r = srow + c * 8;
      int grow = brow + r;
      if (grow >= N) grow = N - 1;
      gload_lds16(Asrc + (size_t)grow * DFEAT + k0 + (skb >> 1),
                  (char*)As + (w * 32 + c * 8) * 128);
      gload_lds16(Bsrc + (size_t)(bcol + r) * DFEAT + k0 + (skb >> 1),
                  (char*)Bs + (w * 32 + c * 8) * 128);
    }
    __syncthreads();  // drains vmcnt(0): tiles ready
#pragma unroll
    for (int ks = 0; ks < 2; ++ks) {
      bf16x8 af[4], bfr[4];
#pragma unroll
      for (int i = 0; i < 4; ++i) {
        int row = wm * 64 + i * 16 + (lane & 15);
        int kb = (ks * 64 + ((lane >> 4) << 4)) ^ ((row & 7) << 4);
        af[i] = *(const bf16x8*)((const char*)As + row * 128 + kb);
      }
#pragma unroll
      for (int j = 0; j < 4; ++j) {
        int row = wn * 64 + j * 16 + (lane & 15);
        int kb = (ks * 64 + ((lane >> 4) << 4)) ^ ((row & 7) << 4);
        bfr[j] = *(const bf16x8*)((const char*)Bs + row * 128 + kb);
      }
#pragma unroll
      for (int i = 0; i < 4; ++i)
#pragma unroll
        for (int j = 0; j < 4; ++j)
          acc[i][j] = __builtin_amdgcn_mfma_f32_16x16x32_bf16(af[i], bfr[j], acc[i][j], 0, 0, 0);
    }
  }

#pragma unroll
  for (int i = 0; i < 4; ++i) {
    int rowb = brow + wm * 64 + i * 16 + (lane >> 4) * 4;
#pragma unroll
    for (int j = 0; j < 4; ++j) {
      int col = bcol + wn * 64 + j * 16 + (lane & 15);
      float b = bias[col];
#pragma unroll
      for (int q = 0; q < 4; ++q) {
        int r = rowb + q;
        if (r < N) C[(size_t)r * DFEAT + col] = acc[i][j][q] + b;
      }
    }
  }
}

// ---------------- launch ----------------

extern "C" void kernel_launch(void* const* d_in, const int* in_sizes, int n_in,
                              void* d_out, int out_size, void* d_ws, size_t ws_size,
                              hipStream_t stream) {
  const float* x = (const float*)d_in[0];
  const int* ei = (const int*)d_in[1];
  const float* weight = (const float*)d_in[2];
  const float* bias = (const float*)d_in[3];
  float* out = (float*)d_out;

  int N = in_sizes[0] / DFEAT;
  int E = in_sizes[1] / 2;
  const int* ei0 = ei;
  const int* ei1 = ei + E;

  char* ws = (char*)d_ws;
  size_t off = 0;
  auto alloc = [&](size_t bytes) {
    void* p = ws + off;
    off = (off + bytes + 255) & ~(size_t)255;
    return p;
  };
  int* cnt = (int*)alloc((size_t)2 * N * sizeof(int));
  int* cursor = cnt + N;
  int* rowptr = (int*)alloc((size_t)(N + 1) * sizeof(int));
  float* dis = (float*)alloc((size_t)N * sizeof(float));
  int* cols = (int*)alloc((size_t)E * sizeof(int));
  float* vals = (float*)alloc((size_t)E * sizeof(float));
  unsigned short* xbf = (unsigned short*)alloc((size_t)N * DFEAT * 2);
  unsigned short* B1 = (unsigned short*)alloc((size_t)N * DFEAT * 2);
  unsigned short* B2 = (unsigned short*)alloc((size_t)N * DFEAT * 2);
  unsigned short* B3 = (unsigned short*)alloc((size_t)N * DFEAT * 2);
  unsigned short* WT = (unsigned short*)alloc((size_t)4 * DFEAT * DFEAT * 2);

  hipMemsetAsync(cnt, 0, (size_t)2 * N * sizeof(int), stream);

  int eb = (E + 255) / 256;
  k_count<<<eb, 256, 0, stream>>>(ei0, E, cnt);
  k_scan<<<1, 1024, 0, stream>>>(cnt, N, E, rowptr, dis);
  k_scatter<<<eb, 256, 0, stream>>>(ei0, ei1, E, rowptr, cursor, dis, cols, vals);

  int n4 = N * DFEAT / 4;
  k_f2bf<<<(n4 + 255) / 256, 256, 0, stream>>>(x, xbf, n4);
  k_wt<<<4 * DFEAT * DFEAT / 256, 256, 0, stream>>>(weight, WT);

  // T1 = L x ; T2 = 2 L T1 - x ; T3 = 2 L T2 - T1
  k_spmm_bf<<<N, 256, 0, stream>>>(xbf, xbf, B1, rowptr, cols, vals, dis, 1.0f, 0.0f);
  k_spmm_bf<<<N, 256, 0, stream>>>(B1, xbf, B2, rowptr, cols, vals, dis, 2.0f, -1.0f);
  k_spmm_bf<<<N, 256, 0, stream>>>(B2, B1, B3, rowptr, cols, vals, dis, 2.0f, -1.0f);

  dim3 ggrid((N + 127) / 128, DFEAT / 128);
  k_gemm4<<<ggrid, 256, 0, stream>>>(xbf, B1, B2, B3, WT, bias, out, N);
}

// Round 3
// 358.379 us; speedup vs baseline: 3.0025x; 1.5433x over previous
//
#include <hip/hip_runtime.h>
#include <hip/hip_bf16.h>

#define DFEAT 256

typedef __attribute__((ext_vector_type(8))) short bf16x8;
typedef __attribute__((ext_vector_type(4))) float f32x4;

__device__ __forceinline__ float bf2f(unsigned short u) {
  return __builtin_bit_cast(float, ((unsigned)u) << 16);
}
__device__ __forceinline__ unsigned short f2bf(float f) {
  __hip_bfloat16 h = __float2bfloat16(f);  // RTNE
  return *reinterpret_cast<unsigned short*>(&h);
}
__device__ __forceinline__ void gload_lds16(const void* g, void* l) {
  __builtin_amdgcn_global_load_lds(
      (const __attribute__((address_space(1))) void*)g,
      (__attribute__((address_space(3))) void*)l, 16, 0, 0);
}

// ---------------- CSR construction ----------------

__global__ void k_count(const int* __restrict__ ei0, int E, int* __restrict__ cnt) {
  int i = blockIdx.x * blockDim.x + threadIdx.x;
  if (i < E) atomicAdd(&cnt[ei0[i]], 1);
}

// phase 1: per-block inclusive scan of cnt; also dis = rsqrt(deg+1)
__global__ __launch_bounds__(256) void k_scan1(const int* __restrict__ cnt, int N,
                                               int* __restrict__ incl,
                                               int* __restrict__ bsum,
                                               float* __restrict__ dis) {
  __shared__ int sh[256];
  int t = threadIdx.x;
  int i = blockIdx.x * 256 + t;
  int v = (i < N) ? cnt[i] : 0;
  sh[t] = v;
  __syncthreads();
  for (int o = 1; o < 256; o <<= 1) {
    int u = (t >= o) ? sh[t - o] : 0;
    __syncthreads();
    sh[t] += u;
    __syncthreads();
  }
  if (i < N) {
    incl[i] = sh[t];
    dis[i] = rsqrtf((float)(v + 1));
  }
  if (t == 255) bsum[blockIdx.x] = sh[255];
}

// phase 2: exclusive scan of block sums (nb <= 256)
__global__ __launch_bounds__(256) void k_scan2(const int* __restrict__ bsum, int nb,
                                               int* __restrict__ boff) {
  __shared__ int sh[256];
  int t = threadIdx.x;
  int v = (t < nb) ? bsum[t] : 0;
  sh[t] = v;
  __syncthreads();
  for (int o = 1; o < 256; o <<= 1) {
    int u = (t >= o) ? sh[t - o] : 0;
    __syncthreads();
    sh[t] += u;
    __syncthreads();
  }
  if (t < nb) boff[t] = sh[t] - v;  // exclusive
}

// phase 3: rowptr[i] = boff[b] + incl[i] - cnt[i]
__global__ __launch_bounds__(256) void k_scan3(const int* __restrict__ cnt,
                                               const int* __restrict__ incl,
                                               const int* __restrict__ boff, int N, int E,
                                               int* __restrict__ rowptr) {
  int i = blockIdx.x * 256 + threadIdx.x;
  if (i < N) rowptr[i] = boff[blockIdx.x] + incl[i] - cnt[i];
  if (i == 0) rowptr[N] = E;
}

__global__ void k_scatter(const int* __restrict__ ei0, const int* __restrict__ ei1, int E,
                          const int* __restrict__ rowptr, int* __restrict__ cursor,
                          const float* __restrict__ dis,
                          int* __restrict__ cols, float* __restrict__ vals) {
  int i = blockIdx.x * blockDim.x + threadIdx.x;
  if (i >= E) return;
  int r = ei0[i];
  int c = ei1[i];
  int pos = rowptr[r] + atomicAdd(&cursor[r], 1);
  cols[pos] = c;
  vals[pos] = -dis[r] * dis[c] + (r == c ? 1.0f : 0.0f);
}

// ---------------- converts ----------------

__global__ void k_f2bf(const float* __restrict__ src, unsigned short* __restrict__ dst,
                       int n4) {
  int i = blockIdx.x * blockDim.x + threadIdx.x;
  if (i >= n4) return;
  float4 f = *(const float4*)(src + (size_t)i * 4);
  ushort4 u;
  u.x = f2bf(f.x); u.y = f2bf(f.y); u.z = f2bf(f.z); u.w = f2bf(f.w);
  *(ushort4*)(dst + (size_t)i * 4) = u;
}

// W[4][256][256] (g,k,n) -> WT[4][256][256] (g,n,k) bf16
__global__ void k_wt(const float* __restrict__ W, unsigned short* __restrict__ WT) {
  int idx = blockIdx.x * 256 + threadIdx.x;
  int n = idx & 255;
  int k = (idx >> 8) & 255;
  int g = idx >> 16;
  WT[(g << 16) | (n << 8) | k] = f2bf(W[idx]);
}

// ---------------- SpMM (bf16): y = alpha * (L v) + beta * w ----------------
// 256 threads = 8 edge slots (half-wave each) x 32 lanes; lane covers 8 feats (16B).
// Edge loop unrolled x2 for independent gather chains.

__global__ __launch_bounds__(256) void k_spmm_bf(
    const unsigned short* __restrict__ v, const unsigned short* __restrict__ w,
    unsigned short* __restrict__ y,
    const int* __restrict__ rowptr, const int* __restrict__ cols,
    const float* __restrict__ vals, const float* __restrict__ dis,
    float alpha, float beta) {
  __shared__ float red[3][32][9];  // +1 pad: conflict-free scalar writes
  int r = blockIdx.x;
  int lane = threadIdx.x & 63;
  int w4 = threadIdx.x >> 6;   // wave 0..3
  int half = lane >> 5;
  int l32 = lane & 31;
  int slot = w4 * 2 + half;    // 0..7
  int fo = l32 * 8;            // 8 feats per lane
  float acc[8] = {};
  int e0 = rowptr[r], e1 = rowptr[r + 1];

  int e = e0 + slot;
  for (; e + 8 < e1; e += 16) {
    int cA = cols[e], cB = cols[e + 8];
    float lA = vals[e], lB = vals[e + 8];
    uint4 uA = *(const uint4*)(v + (size_t)cA * DFEAT + fo);
    uint4 uB = *(const uint4*)(v + (size_t)cB * DFEAT + fo);
    const unsigned int* wa = &uA.x;
    const unsigned int* wb = &uB.x;
#pragma unroll
    for (int j = 0; j < 4; ++j) {
      acc[2 * j]     += lA * bf2f(wa[j] & 0xffff) + lB * bf2f(wb[j] & 0xffff);
      acc[2 * j + 1] += lA * bf2f(wa[j] >> 16)    + lB * bf2f(wb[j] >> 16);
    }
  }
  if (e < e1) {
    int c = cols[e];
    float lv = vals[e];
    uint4 u = *(const uint4*)(v + (size_t)c * DFEAT + fo);
    const unsigned int* wu = &u.x;
#pragma unroll
    for (int j = 0; j < 4; ++j) {
      acc[2 * j]     += lv * bf2f(wu[j] & 0xffff);
      acc[2 * j + 1] += lv * bf2f(wu[j] >> 16);
    }
  }

  // cross-half reduce within wave
#pragma unroll
  for (int j = 0; j < 8; ++j) acc[j] += __shfl_xor(acc[j], 32);

  if (w4 && !half) {
#pragma unroll
    for (int j = 0; j < 8; ++j) red[w4 - 1][l32][j] = acc[j];
  }
  __syncthreads();
  if (w4 == 0 && !half) {
    float dr = dis[r];
    float sc = 1.0f - dr * dr;  // self-loop Laplacian value
    uint4 uv = *(const uint4*)(v + (size_t)r * DFEAT + fo);
    const unsigned int* vu = &uv.x;
    float wv[8] = {};
    if (beta != 0.0f) {
      uint4 uw = *(const uint4*)(w + (size_t)r * DFEAT + fo);
      const unsigned int* wu = &uw.x;
#pragma unroll
      for (int j = 0; j < 4; ++j) {
        wv[2 * j] = bf2f(wu[j] & 0xffff);
        wv[2 * j + 1] = bf2f(wu[j] >> 16);
      }
    }
    ushort4 o[2];
    unsigned short* op = &o[0].x;
#pragma unroll
    for (int j = 0; j < 8; ++j) {
      float a = acc[j] + red[0][l32][j] + red[1][l32][j] + red[2][l32][j];
      float selfv = (j & 1) ? bf2f(vu[j >> 1] >> 16) : bf2f(vu[j >> 1] & 0xffff);
      a += sc * selfv;
      op[j] = f2bf(alpha * a + beta * wv[j]);
    }
    *(uint4*)(y + (size_t)r * DFEAT + fo) = *(const uint4*)&o[0];
  }
}

// ---------------- fused MFMA GEMM: out = sum_g Ag @ Wg + bias ----------------

__global__ __launch_bounds__(256) void k_gemm4(
    const unsigned short* __restrict__ A0, const unsigned short* __restrict__ A1,
    const unsigned short* __restrict__ A2, const unsigned short* __restrict__ A3,
    const unsigned short* __restrict__ WT,  // [4][256][256] (g,n,k)
    const float* __restrict__ bias, float* __restrict__ C, int N) {
  __shared__ __align__(16) unsigned short As[128 * 64];
  __shared__ __align__(16) unsigned short Bs[128 * 64];
  int tid = threadIdx.x;
  int lane = tid & 63;
  int w = tid >> 6;
  int wm = w >> 1, wn = w & 1;
  int brow = blockIdx.x * 128;
  int bcol = blockIdx.y * 128;

  f32x4 acc[4][4] = {};

  int srow = w * 32 + (lane >> 3);
  int skb = ((lane & 7) ^ (lane >> 3)) << 4;

  for (int it = 0; it < 16; ++it) {
    int g = it >> 2;
    int k0 = (it & 3) * 64;
    const unsigned short* Asrc = g == 0 ? A0 : g == 1 ? A1 : g == 2 ? A2 : A3;
    const unsigned short* Bsrc = WT + (g << 16);
    __syncthreads();
#pragma unroll
    for (int c = 0; c < 4; ++c) {
      int r = srow + c * 8;
      int grow = brow + r;
      if (grow >= N) grow = N - 1;
      gload_lds16(Asrc + (size_t)grow * DFEAT + k0 + (skb >> 1),
                  (char*)As + (w * 32 + c * 8) * 128);
      gload_lds16(Bsrc + (size_t)(bcol + r) * DFEAT + k0 + (skb >> 1),
                  (char*)Bs + (w * 32 + c * 8) * 128);
    }
    __syncthreads();
#pragma unroll
    for (int ks = 0; ks < 2; ++ks) {
      bf16x8 af[4], bfr[4];
#pragma unroll
      for (int i = 0; i < 4; ++i) {
        int row = wm * 64 + i * 16 + (lane & 15);
        int kb = (ks * 64 + ((lane >> 4) << 4)) ^ ((row & 7) << 4);
        af[i] = *(const bf16x8*)((const char*)As + row * 128 + kb);
      }
#pragma unroll
      for (int j = 0; j < 4; ++j) {
        int row = wn * 64 + j * 16 + (lane & 15);
        int kb = (ks * 64 + ((lane >> 4) << 4)) ^ ((row & 7) << 4);
        bfr[j] = *(const bf16x8*)((const char*)Bs + row * 128 + kb);
      }
#pragma unroll
      for (int i = 0; i < 4; ++i)
#pragma unroll
        for (int j = 0; j < 4; ++j)
          acc[i][j] = __builtin_amdgcn_mfma_f32_16x16x32_bf16(af[i], bfr[j], acc[i][j], 0, 0, 0);
    }
  }

#pragma unroll
  for (int i = 0; i < 4; ++i) {
    int rowb = brow + wm * 64 + i * 16 + (lane >> 4) * 4;
#pragma unroll
    for (int j = 0; j < 4; ++j) {
      int col = bcol + wn * 64 + j * 16 + (lane & 15);
      float b = bias[col];
#pragma unroll
      for (int q = 0; q < 4; ++q) {
        int r = rowb + q;
        if (r < N) C[(size_t)r * DFEAT + col] = acc[i][j][q] + b;
      }
    }
  }
}

// ---------------- launch ----------------

extern "C" void kernel_launch(void* const* d_in, const int* in_sizes, int n_in,
                              void* d_out, int out_size, void* d_ws, size_t ws_size,
                              hipStream_t stream) {
  const float* x = (const float*)d_in[0];
  const int* ei = (const int*)d_in[1];
  const float* weight = (const float*)d_in[2];
  const float* bias = (const float*)d_in[3];
  float* out = (float*)d_out;

  int N = in_sizes[0] / DFEAT;
  int E = in_sizes[1] / 2;
  const int* ei0 = ei;
  const int* ei1 = ei + E;

  char* ws = (char*)d_ws;
  size_t off = 0;
  auto alloc = [&](size_t bytes) {
    void* p = ws + off;
    off = (off + bytes + 255) & ~(size_t)255;
    return p;
  };
  int* cnt = (int*)alloc((size_t)2 * N * sizeof(int));
  int* cursor = cnt + N;
  int* rowptr = (int*)alloc((size_t)(N + 1) * sizeof(int));
  float* dis = (float*)alloc((size_t)N * sizeof(float));
  int* cols = (int*)alloc((size_t)E * sizeof(int));
  float* vals = (float*)alloc((size_t)E * sizeof(float));
  int* incl = (int*)alloc((size_t)N * sizeof(int));
  int* bsum = (int*)alloc(256 * sizeof(int));
  int* boff = (int*)alloc(256 * sizeof(int));
  unsigned short* xbf = (unsigned short*)alloc((size_t)N * DFEAT * 2);
  unsigned short* B1 = (unsigned short*)alloc((size_t)N * DFEAT * 2);
  unsigned short* B2 = (unsigned short*)alloc((size_t)N * DFEAT * 2);
  unsigned short* B3 = (unsigned short*)alloc((size_t)N * DFEAT * 2);
  unsigned short* WT = (unsigned short*)alloc((size_t)4 * DFEAT * DFEAT * 2);

  hipMemsetAsync(cnt, 0, (size_t)2 * N * sizeof(int), stream);

  int eb = (E + 255) / 256;
  int nb = (N + 255) / 256;
  k_count<<<eb, 256, 0, stream>>>(ei0, E, cnt);
  k_scan1<<<nb, 256, 0, stream>>>(cnt, N, incl, bsum, dis);
  k_scan2<<<1, 256, 0, stream>>>(bsum, nb, boff);
  k_scan3<<<nb, 256, 0, stream>>>(cnt, incl, boff, N, E, rowptr);
  k_scatter<<<eb, 256, 0, stream>>>(ei0, ei1, E, rowptr, cursor, dis, cols, vals);

  int n4 = N * DFEAT / 4;
  k_f2bf<<<(n4 + 255) / 256, 256, 0, stream>>>(x, xbf, n4);
  k_wt<<<4 * DFEAT * DFEAT / 256, 256, 0, stream>>>(weight, WT);

  // T1 = L x ; T2 = 2 L T1 - x ; T3 = 2 L T2 - T1
  k_spmm_bf<<<N, 256, 0, stream>>>(xbf, xbf, B1, rowptr, cols, vals, dis, 1.0f, 0.0f);
  k_spmm_bf<<<N, 256, 0, stream>>>(B1, xbf, B2, rowptr, cols, vals, dis, 2.0f, -1.0f);
  k_spmm_bf<<<N, 256, 0, stream>>>(B2, B1, B3, rowptr, cols, vals, dis, 2.0f, -1.0f);

  dim3 ggrid((N + 127) / 128, DFEAT / 128);
  k_gemm4<<<ggrid, 256, 0, stream>>>(xbf, B1, B2, B3, WT, bias, out, N);
}